// Round 1
// baseline (11559.365 us; speedup 1.0000x reference)
//
#include <hip/hip_runtime.h>
#include <hip/hip_fp16.h>

#define BLOCK 256
#define HD 64
#define TT 8
#define INP 6

__device__ __forceinline__ float frcp(float x){ return __builtin_amdgcn_rcpf(x); }
// sigmoid(x) = 1/(1+2^(-x*log2e))
__device__ __forceinline__ float sigm(float x){
    return frcp(1.0f + __builtin_exp2f(-1.442695040888963f*x));
}
// tanh(x) = 1 - 2/(1+2^(2x*log2e))
__device__ __forceinline__ float ftanh(float x){
    return 1.0f - 2.0f*frcp(1.0f + __builtin_exp2f(2.885390081777927f*x));
}

__global__ void __launch_bounds__(BLOCK, 1)
lstm_fused(const float* __restrict__ x,
           const float* __restrict__ Wih0, const float* __restrict__ Whh0,
           const float* __restrict__ bih0, const float* __restrict__ bhh0,
           const float* __restrict__ Wih1, const float* __restrict__ Whh1,
           const float* __restrict__ bih1, const float* __restrict__ bhh1,
           const float* __restrict__ Wfc,  const float* __restrict__ bfc,
           float* __restrict__ out)
{
    extern __shared__ float smem[];
    float*  c0s = smem;                          // [HD][BLOCK] fp32, 64 KiB
    float*  c1s = smem +   HD*BLOCK;             // [HD][BLOCK] fp32, 64 KiB
    __half* hns = (__half*)(smem + 2*HD*BLOCK);  // [HD][BLOCK] fp16, 32 KiB

    const int tid = threadIdx.x;
    const int b   = blockIdx.x*BLOCK + tid;

    float h0[HD], h1[HD];
#pragma unroll
    for (int k=0;k<HD;k++){
        h0[k]=0.f; h1[k]=0.f;
        c0s[k*BLOCK+tid]=0.f;
        c1s[k*BLOCK+tid]=0.f;
    }

    const float* xrow = x + (size_t)b*(TT*INP);
    float fcacc = 0.f;

    for (int t=0;t<TT;t++){
        // x_t : 6 floats (8B-aligned: byte offset 192*b + 24*t)
        float2 xa  = *(const float2*)(xrow + t*INP);
        float2 xbv = *(const float2*)(xrow + t*INP + 2);
        float2 xc  = *(const float2*)(xrow + t*INP + 4);

        // ---------------- layer 0 ----------------
        for (int k=0;k<HD;k++){
            float ai = bih0[k]      + bhh0[k];
            float af = bih0[k+HD]   + bhh0[k+HD];
            float ag = bih0[k+2*HD] + bhh0[k+2*HD];
            float ao = bih0[k+3*HD] + bhh0[k+3*HD];
            const float* pi = Wih0 + k*INP;
            const float* pf = Wih0 + (k+HD)*INP;
            const float* pg = Wih0 + (k+2*HD)*INP;
            const float* po = Wih0 + (k+3*HD)*INP;
            ai += pi[0]*xa.x + pi[1]*xa.y + pi[2]*xbv.x + pi[3]*xbv.y + pi[4]*xc.x + pi[5]*xc.y;
            af += pf[0]*xa.x + pf[1]*xa.y + pf[2]*xbv.x + pf[3]*xbv.y + pf[4]*xc.x + pf[5]*xc.y;
            ag += pg[0]*xa.x + pg[1]*xa.y + pg[2]*xbv.x + pg[3]*xbv.y + pg[4]*xc.x + pg[5]*xc.y;
            ao += po[0]*xa.x + po[1]*xa.y + po[2]*xbv.x + po[3]*xbv.y + po[4]*xc.x + po[5]*xc.y;
            const float* wi = Whh0 + k*HD;
            const float* wf = Whh0 + (k+HD)*HD;
            const float* wg = Whh0 + (k+2*HD)*HD;
            const float* wo = Whh0 + (k+3*HD)*HD;
#pragma unroll
            for (int j=0;j<HD;j++){
                float hv = h0[j];
                ai += wi[j]*hv; af += wf[j]*hv; ag += wg[j]*hv; ao += wo[j]*hv;
            }
            float ig=sigm(ai), fg=sigm(af), gv=ftanh(ag), og=sigm(ao);
            float c = fg*c0s[k*BLOCK+tid] + ig*gv;
            c0s[k*BLOCK+tid] = c;
            hns[k*BLOCK+tid] = __float2half(og*ftanh(c));
        }
#pragma unroll
        for (int k=0;k<HD;k++) h0[k] = __half2float(hns[k*BLOCK+tid]);

        // ---------------- layer 1 ----------------
        for (int k=0;k<HD;k++){
            float ai = bih1[k]      + bhh1[k];
            float af = bih1[k+HD]   + bhh1[k+HD];
            float ag = bih1[k+2*HD] + bhh1[k+2*HD];
            float ao = bih1[k+3*HD] + bhh1[k+3*HD];
            const float* ui = Wih1 + k*HD;
            const float* uf = Wih1 + (k+HD)*HD;
            const float* ug = Wih1 + (k+2*HD)*HD;
            const float* uo = Wih1 + (k+3*HD)*HD;
            const float* wi = Whh1 + k*HD;
            const float* wf = Whh1 + (k+HD)*HD;
            const float* wg = Whh1 + (k+2*HD)*HD;
            const float* wo = Whh1 + (k+3*HD)*HD;
#pragma unroll
            for (int j=0;j<HD;j++){
                float xv = h0[j];
                float hv = h1[j];
                ai += ui[j]*xv + wi[j]*hv;
                af += uf[j]*xv + wf[j]*hv;
                ag += ug[j]*xv + wg[j]*hv;
                ao += uo[j]*xv + wo[j]*hv;
            }
            float ig=sigm(ai), fg=sigm(af), gv=ftanh(ag), og=sigm(ao);
            float c = fg*c1s[k*BLOCK+tid] + ig*gv;
            c1s[k*BLOCK+tid] = c;
            float hnew = og*ftanh(c);
            hns[k*BLOCK+tid] = __float2half(hnew);
            if (t == TT-1) fcacc += Wfc[k]*hnew;   // FC from fp32 h, not the fp16 roundtrip
        }
#pragma unroll
        for (int k=0;k<HD;k++) h1[k] = __half2float(hns[k*BLOCK+tid]);
    }
    out[b] = fcacc + bfc[0];
}

extern "C" void kernel_launch(void* const* d_in, const int* in_sizes, int n_in,
                              void* d_out, int out_size, void* d_ws, size_t ws_size,
                              hipStream_t stream) {
    const float* x    = (const float*)d_in[0];
    const float* Wih0 = (const float*)d_in[1];
    const float* Whh0 = (const float*)d_in[2];
    const float* bih0 = (const float*)d_in[3];
    const float* bhh0 = (const float*)d_in[4];
    const float* Wih1 = (const float*)d_in[5];
    const float* Whh1 = (const float*)d_in[6];
    const float* bih1 = (const float*)d_in[7];
    const float* bhh1 = (const float*)d_in[8];
    const float* Wfc  = (const float*)d_in[9];
    const float* bfc  = (const float*)d_in[10];
    float* out = (float*)d_out;

    const int B = in_sizes[0] / (TT*INP);          // 131072
    const size_t shmem = (size_t)(2*HD*BLOCK)*sizeof(float)
                       + (size_t)HD*BLOCK*sizeof(__half);   // 163840 B
    hipFuncSetAttribute(reinterpret_cast<const void*>(lstm_fused),
                        hipFuncAttributeMaxDynamicSharedMemorySize, (int)shmem);
    lstm_fused<<<dim3(B/BLOCK), dim3(BLOCK), shmem, stream>>>(
        x, Wih0, Whh0, bih0, bhh0, Wih1, Whh1, bih1, bhh1, Wfc, bfc, out);
}

// Round 2
// 482.545 us; speedup vs baseline: 23.9550x; 23.9550x over previous
//
#include <hip/hip_runtime.h>

#define BLOCK 256
#define TT 8
#define INP 6
#define HDIM 64
#define LDH 72   // f16 elems per h row (64 + 8 pad); 144B rows keep 16B alignment

typedef _Float16 f16;
typedef __attribute__((ext_vector_type(8))) _Float16 f16x8;
typedef __attribute__((ext_vector_type(16))) float f32x16;

// LDS layout in f16 units (after 640 floats of bias/wfc):
#define WIH0_OFF 0                      // 8 frags  * 512 f16 (K=16, k>=6 zero)
#define WHH0_OFF 4096                   // 32 frags * 512
#define WIH1_OFF 20480                  // 32 frags * 512
#define WHH1_OFF 36864                  // 32 frags * 512
#define H0_OFF   53248                  // 128 rows * LDH
#define H1_OFF   (53248 + 128*LDH)
#define NF16     (53248 + 2*128*LDH)    // 71680 f16
#define NF32     640                    // 512 bias + 64 wfc + 1 bfc (+pad)

__device__ __forceinline__ float sigm(float x){
    return __builtin_amdgcn_rcpf(1.0f + __builtin_exp2f(-1.442695040888963f*x));
}
__device__ __forceinline__ float ftanh(float x){
    return 1.0f - 2.0f*__builtin_amdgcn_rcpf(1.0f + __builtin_exp2f(2.885390081777927f*x));
}

__global__ void __launch_bounds__(BLOCK, 1)
lstm_mfma(const float* __restrict__ x,
          const float* __restrict__ Wih0, const float* __restrict__ Whh0,
          const float* __restrict__ bih0, const float* __restrict__ bhh0,
          const float* __restrict__ Wih1, const float* __restrict__ Whh1,
          const float* __restrict__ bih1, const float* __restrict__ bhh1,
          const float* __restrict__ Wfc,  const float* __restrict__ bfc,
          float* __restrict__ out)
{
    extern __shared__ char smem[];
    float* fbias = (float*)smem;                 // [0..255]=b0, [256..511]=b1
    float* fwfc  = fbias + 512;                  // [0..63]=Wfc, [64]=bfc
    f16*   fh    = (f16*)(smem + NF32*4);

    const int tid = threadIdx.x;

    // ---- pack weight matrices into B-fragment layout ----
    // frag elem (lane l2, e): B[k][n] = W[n][k], n=(fg>>2)*32+(l2&31), k=(fg&3)*16+(l2>>5)*8+e
    for (int i = tid; i < 3*16384; i += BLOCK){
        int m  = i >> 14;
        int j  = i & 16383;
        int e  = j & 7;
        int l2 = (j >> 3) & 63;
        int fg = j >> 9;
        int n  = (fg >> 2)*32 + (l2 & 31);
        int k  = (fg & 3)*16 + (l2 >> 5)*8 + e;
        const float* W = (m==0)? Whh0 : (m==1)? Wih1 : Whh1;
        int off = (m==0)? WHH0_OFF : (m==1)? WIH1_OFF : WHH1_OFF;
        fh[off + fg*512 + (j & 511)] = (f16)W[n*HDIM + k];
    }
    // Wih0: [256][6], padded to K=16
    for (int i = tid; i < 4096; i += BLOCK){
        int e = i & 7, l2 = (i >> 3) & 63, nt = i >> 9;
        int n = nt*32 + (l2 & 31);
        int k = (l2 >> 5)*8 + e;
        fh[WIH0_OFF + nt*512 + (i & 511)] = (k < INP)? (f16)Wih0[n*INP + k] : (f16)0.0f;
    }
    for (int i = tid; i < 256; i += BLOCK){
        fbias[i]       = bih0[i] + bhh0[i];
        fbias[256 + i] = bih1[i] + bhh1[i];
    }
    if (tid < 64) fwfc[tid] = Wfc[tid];
    if (tid == 0) fwfc[64] = bfc[0];
    __syncthreads();

    const int l     = tid & 63;
    const int w     = tid >> 6;
    const int rlo   = l & 31;     // A row within 32-row tile; also B col
    const int khalf = l >> 5;     // k-half selector
    const int row0  = blockIdx.x*128 + w*32;

    f16* h0p = fh + H0_OFF + (w*32)*LDH;   // per-wave private 32 rows
    f16* h1p = fh + H1_OFF + (w*32)*LDH;

    float c0[32], c1[32];
#pragma unroll
    for (int i=0;i<32;i++){ c0[i]=0.f; c1[i]=0.f; }

    const float* xrow = x + (size_t)(row0 + rlo)*TT*INP;

#pragma unroll 1
    for (int t=0;t<TT;t++){
        // x fragment: A row=rlo, k=(khalf)*8+e; only k<6 nonzero
        f16x8 xf;
#pragma unroll
        for (int i2=0;i2<8;i2++) xf[i2] = (f16)0.f;
        if (khalf == 0){
            const float* xp = xrow + t*INP;
            xf[0]=(f16)xp[0]; xf[1]=(f16)xp[1]; xf[2]=(f16)xp[2];
            xf[3]=(f16)xp[3]; xf[4]=(f16)xp[4]; xf[5]=(f16)xp[5];
        }

        // ================= layer 0 =================
        f32x16 acc[8];
#pragma unroll
        for (int nt=0;nt<8;nt++){
            float bv = fbias[nt*32 + rlo];
#pragma unroll
            for (int r=0;r<16;r++) acc[nt][r] = bv;
        }
#pragma unroll
        for (int nt=0;nt<8;nt++){
            f16x8 bf = *(const f16x8*)(fh + WIH0_OFF + nt*512 + l*8);
            acc[nt] = __builtin_amdgcn_mfma_f32_32x32x16_f16(xf, bf, acc[nt], 0,0,0);
        }
        if (t > 0){
#pragma unroll
            for (int kt=0;kt<4;kt++){
                f16x8 hf = *(const f16x8*)(h0p + rlo*LDH + kt*16 + khalf*8);
#pragma unroll
                for (int nt=0;nt<8;nt++){
                    f16x8 bf = *(const f16x8*)(fh + WHH0_OFF + (nt*4+kt)*512 + l*8);
                    acc[nt] = __builtin_amdgcn_mfma_f32_32x32x16_f16(hf, bf, acc[nt], 0,0,0);
                }
            }
        }
        // elementwise L0 -> c0, h0 (C/D layout: col=rlo+32s, row=(r&3)+8*(r>>2)+4*khalf)
#pragma unroll
        for (int s=0;s<2;s++){
#pragma unroll
            for (int r=0;r<16;r++){
                float ig = sigm (acc[0+s][r]);
                float fg = sigm (acc[2+s][r]);
                float gg = ftanh(acc[4+s][r]);
                float og = sigm (acc[6+s][r]);
                float c  = fg*c0[s*16+r] + ig*gg;
                c0[s*16+r] = c;
                float hv = og*ftanh(c);
                h0p[((r&3) + 8*(r>>2) + 4*khalf)*LDH + rlo + 32*s] = (f16)hv;
            }
        }
        __syncthreads();

        // ================= layer 1 =================
#pragma unroll
        for (int nt=0;nt<8;nt++){
            float bv = fbias[256 + nt*32 + rlo];
#pragma unroll
            for (int r=0;r<16;r++) acc[nt][r] = bv;
        }
#pragma unroll
        for (int kt=0;kt<4;kt++){
            f16x8 hf = *(const f16x8*)(h0p + rlo*LDH + kt*16 + khalf*8);
#pragma unroll
            for (int nt=0;nt<8;nt++){
                f16x8 bf = *(const f16x8*)(fh + WIH1_OFF + (nt*4+kt)*512 + l*8);
                acc[nt] = __builtin_amdgcn_mfma_f32_32x32x16_f16(hf, bf, acc[nt], 0,0,0);
            }
        }
        if (t > 0){
#pragma unroll
            for (int kt=0;kt<4;kt++){
                f16x8 hf = *(const f16x8*)(h1p + rlo*LDH + kt*16 + khalf*8);
#pragma unroll
                for (int nt=0;nt<8;nt++){
                    f16x8 bf = *(const f16x8*)(fh + WHH1_OFF + (nt*4+kt)*512 + l*8);
                    acc[nt] = __builtin_amdgcn_mfma_f32_32x32x16_f16(hf, bf, acc[nt], 0,0,0);
                }
            }
        }
#pragma unroll
        for (int s=0;s<2;s++){
#pragma unroll
            for (int r=0;r<16;r++){
                float ig = sigm (acc[0+s][r]);
                float fg = sigm (acc[2+s][r]);
                float gg = ftanh(acc[4+s][r]);
                float og = sigm (acc[6+s][r]);
                float c  = fg*c1[s*16+r] + ig*gg;
                c1[s*16+r] = c;
                float hv = og*ftanh(c);
                h1p[((r&3) + 8*(r>>2) + 4*khalf)*LDH + rlo + 32*s] = (f16)hv;
            }
        }
        __syncthreads();
    }

    // ---- FC epilogue: one row per thread (tid<128) ----
    if (tid < 128){
        const f16* hp = fh + H1_OFF + tid*LDH;
        float sacc = fwfc[64];
#pragma unroll
        for (int u=0;u<HDIM;u++) sacc += fwfc[u]*(float)hp[u];
        out[(size_t)blockIdx.x*128 + tid] = sacc;
    }
}

extern "C" void kernel_launch(void* const* d_in, const int* in_sizes, int n_in,
                              void* d_out, int out_size, void* d_ws, size_t ws_size,
                              hipStream_t stream) {
    const float* x    = (const float*)d_in[0];
    const float* Wih0 = (const float*)d_in[1];
    const float* Whh0 = (const float*)d_in[2];
    const float* bih0 = (const float*)d_in[3];
    const float* bhh0 = (const float*)d_in[4];
    const float* Wih1 = (const float*)d_in[5];
    const float* Whh1 = (const float*)d_in[6];
    const float* bih1 = (const float*)d_in[7];
    const float* bhh1 = (const float*)d_in[8];
    const float* Wfc  = (const float*)d_in[9];
    const float* bfc  = (const float*)d_in[10];
    float* out = (float*)d_out;

    const int B = in_sizes[0] / (TT*INP);          // 131072
    const size_t shmem = (size_t)NF32*4 + (size_t)NF16*2;   // 145920 B
    hipFuncSetAttribute(reinterpret_cast<const void*>(lstm_mfma),
                        hipFuncAttributeMaxDynamicSharedMemorySize, (int)shmem);
    lstm_mfma<<<dim3(B/128), dim3(BLOCK), shmem, stream>>>(
        x, Wih0, Whh0, bih0, bhh0, Wih1, Whh1, bih1, bhh1, Wfc, bfc, out);
}